// Round 18
// baseline (654.298 us; speedup 1.0000x reference)
//
#include <hip/hip_runtime.h>
#include <hip/hip_bf16.h>
#include <cstdint>

// Problem dims
#define B_   8
#define S_   2048
#define D_   1024
#define P_   1365
#define M_   (B_*S_)      // 16384 rows
#define KP   1408         // per-gate padded width (= 11*128, 22*64)
#define NGCP (4*KP)       // 5632 rows of fused weight; layout:
                          //  [0,2KP):   IC region, 22 tiles of 128 rows =
                          //             [i(64t..64t+64) | c(64t..64t+64)]
                          //  [2KP,3KP): f rows;  [3KP,4KP): o rows
#define CHUNK 32          // scan chunk length
#define CMAX (S_/CHUNK)   // 64

typedef __attribute__((ext_vector_type(8))) short bf16x8;
typedef __attribute__((ext_vector_type(4))) float f32x4;
typedef __attribute__((ext_vector_type(4))) unsigned short u16x4;

__device__ __forceinline__ float fast_rcp(float x) {
  return __builtin_amdgcn_rcpf(x);
}
__device__ __forceinline__ float fast_tanh(float x) {
  float e = __expf(2.0f * x);
  return 1.0f - 2.0f * fast_rcp(e + 1.0f);
}
// sigmoid(15*tanh(x/15)), tanh by 3rd-order poly (|x/15| <= ~0.3 here)
__device__ __forceinline__ float softcap_sig(float x) {
  float u = x * (1.0f / 15.0f);
  float z = -x + x * u * u * (1.0f / 3.0f);   // -15*tanh(x/15) approx
  return fast_rcp(1.0f + __expf(z));
}
__device__ __forceinline__ float bf2f(unsigned short u) {
  union { float f; unsigned int i; } x; x.i = ((unsigned)u) << 16; return x.f;
}
__device__ __forceinline__ unsigned short f2bf(float f) {
  __hip_bfloat16 h = __float2bfloat16(f);
  return *reinterpret_cast<unsigned short*>(&h);
}
__device__ __forceinline__ void gload_lds16(const void* g, void* l) {
  __builtin_amdgcn_global_load_lds(
      (const __attribute__((address_space(1))) uint32_t*)g,
      (__attribute__((address_space(3))) uint32_t*)l,
      16, 0, 0);
}

// ---- prep: weights f32 -> bf16, [i64|c64]x22 + f + o layout ----
__global__ void k_prep_wgc(const float* __restrict__ gate_w,
                           const float* __restrict__ cell_w,
                           __hip_bfloat16* __restrict__ wgc) {
  int gid = blockIdx.x * blockDim.x + threadIdx.x;
  int idx = gid * 4;                       // NGCP*1024 total elems
  int r = idx >> 10, c = idx & 1023;
  f32x4 v = {0.f, 0.f, 0.f, 0.f};
  if (r < 2 * KP) {                        // IC region: tile t, [i64|c64]
    int t = r >> 7, lo = r & 127;
    if (lo < 64) {
      int pr = t * 64 + lo;                // i rows (gate 0)
      if (pr < P_) v = __builtin_nontemporal_load((const f32x4*)(gate_w + (size_t)pr * D_ + c));
    } else {
      int pr = t * 64 + (lo - 64);         // c rows (cell)
      if (pr < P_) v = __builtin_nontemporal_load((const f32x4*)(cell_w + (size_t)pr * D_ + c));
    }
  } else if (r < 3 * KP) {                 // f rows (gate 1)
    int pr = r - 2 * KP;
    if (pr < P_) v = __builtin_nontemporal_load((const f32x4*)(gate_w + (size_t)(P_ + pr) * D_ + c));
  } else {                                 // o rows (gate 2)
    int pr = r - 3 * KP;
    if (pr < P_) v = __builtin_nontemporal_load((const f32x4*)(gate_w + (size_t)(2 * P_ + pr) * D_ + c));
  }
  __hip_bfloat16* dst = wgc + idx;
  dst[0] = __float2bfloat16(v.x); dst[1] = __float2bfloat16(v.y);
  dst[2] = __float2bfloat16(v.z); dst[3] = __float2bfloat16(v.w);
}

__global__ void k_prep_wout(const float* __restrict__ out_w,
                            __hip_bfloat16* __restrict__ wout) {
  int gid = blockIdx.x * blockDim.x + threadIdx.x;
  int idx = gid * 4;                       // 1024*1408 total elems
  int d = idx / KP, p = idx - d * KP;
  __hip_bfloat16* dst = wout + idx;
  #pragma unroll
  for (int j = 0; j < 4; ++j) {
    int pp = p + j;
    float v = (pp < P_) ? __builtin_nontemporal_load(out_w + (size_t)d * P_ + pp) : 0.f;
    dst[j] = __float2bfloat16(v);
  }
}

// ---- RMSNorm: per row of D=1024, write bf16 ----
__global__ __launch_bounds__(256) void k_rmsnorm(const float* __restrict__ x,
                                                 const float* __restrict__ w,
                                                 __hip_bfloat16* __restrict__ xn) {
  __shared__ float red[4];
  int m = blockIdx.x;
  int tid = threadIdx.x;
  f32x4 v = __builtin_nontemporal_load(((const f32x4*)(x + (size_t)m * D_)) + tid);
  float ss = v.x * v.x + v.y * v.y + v.z * v.z + v.w * v.w;
  #pragma unroll
  for (int off = 32; off > 0; off >>= 1) ss += __shfl_down(ss, off);
  if ((tid & 63) == 0) red[tid >> 6] = ss;
  __syncthreads();
  float tot = red[0] + red[1] + red[2] + red[3];
  float scale = rsqrtf(tot * (1.0f / (float)D_) + 1e-6f);
  f32x4 wv = ((const f32x4*)w)[tid];
  __hip_bfloat16* o = xn + (size_t)m * D_ + tid * 4;
  o[0] = __float2bfloat16(v.x * scale * wv.x);
  o[1] = __float2bfloat16(v.y * scale * wv.y);
  o[2] = __float2bfloat16(v.z * scale * wv.z);
  o[3] = __float2bfloat16(v.w * scale * wv.w);
}

// ============================================================================
// 128x128-tile GEMM, BK=64, 4 waves (2M x 2N), single-buffered 32KB LDS,
// __launch_bounds__(256,5) -> 5 blocks/CU (LDS 5x32KB = 160KB exactly;
// VGPR 64 << 102 cap). m97/m103 structure: cross-block TLP hides the
// barrier drain. T2 source-swizzle, LDS-staged GATES epilogue, itc fusion,
// NT plane stores.
// r18: bx-CHUNKED XCD mapping — within each XCD's by-band, process bx in
// chunks of 11 (gates NX=44) so the concurrent B working set is ~2.75MB
// (L2-resident) instead of the full 11.5MB (L2 thrash -> 590MB FETCH).
// ============================================================================
template<int LDK, int KT, bool GATES>
__global__ __launch_bounds__(256, 5) void k_gemm128(
    const __hip_bfloat16* __restrict__ A,
    const __hip_bfloat16* __restrict__ Bw,
    __hip_bfloat16* __restrict__ pitc, __hip_bfloat16* __restrict__ pf,
    __hip_bfloat16* __restrict__ po,
    const float* __restrict__ xres, float* __restrict__ out,
    int s0, int sc_shift, int NBY) {
  __shared__ __align__(16) char smem[32768];   // A 16KB + B 16KB (single buf)
  __hip_bfloat16* ldsA = (__hip_bfloat16*)smem;             // [128*64]
  __hip_bfloat16* ldsB = (__hip_bfloat16*)(smem + 16384);   // [128*64]
  const int tid = threadIdx.x;
  const int lane = tid & 63;
  const int wid = tid >> 6;            // 0..3
  const int wm = wid >> 1, wn = wid & 1;
  const int lr = lane & 15, lg = lane >> 4;

  // XCD-chunked bijection with bx-chunking (gridDim.x divisible by 8).
  const int NX = gridDim.x / NBY;
  const int NBYX = NBY >> 3;           // by-rows per XCD
  const int xcd = blockIdx.x & 7;
  const int L = blockIdx.x >> 3;       // 0..cpx-1, cpx = NX*NBYX
  const int W = (NX % 11 == 0) ? 11 : NX;   // bx chunk width
  const int bpc = W * NBYX;
  const int ch = L / bpc;
  const int l2 = L - ch * bpc;
  const int byl = l2 / W;
  const int bxl = l2 - byl * W;
  const int bx = ch * W + bxl;
  const int by = xcd * NBYX + byl;
  const int rl0 = by * 128;            // chunk-local row
  const int col0 = bx * 128;
  const int scm = (1 << sc_shift) - 1;

  auto grow_of = [&](int rl) -> size_t {   // chunk-local row -> global row
    int bb = rl >> sc_shift;
    return (size_t)bb * S_ + s0 + (rl & scm);
  };

  auto stage = [&](int kt) {
    const int k0 = kt * 64;
    #pragma unroll
    for (int it = 0; it < 4; ++it) {
      int off = (it * 256 + tid) * 8;     // 0..8191
      int r = off >> 6, c = off & 63;
      int csrc = c ^ ((r & 7) << 3);      // pre-swizzled source column
      size_t ar = GATES ? grow_of(rl0 + r) : (size_t)(rl0 + r);
      gload_lds16(A + ar * LDK + k0 + csrc, ldsA + off);
      gload_lds16(Bw + (size_t)(col0 + r) * LDK + k0 + csrc, ldsB + off);
    }
  };

  const f32x4 zero = {0.f, 0.f, 0.f, 0.f};
  f32x4 acc[4][4];
  #pragma unroll
  for (int i = 0; i < 4; ++i)
    #pragma unroll
    for (int j = 0; j < 4; ++j) acc[i][j] = zero;

  for (int kt = 0; kt < KT; ++kt) {
    stage(kt);
    __syncthreads();                     // loads resident
    #pragma unroll
    for (int ks = 0; ks < 2; ++ks) {
      bf16x8 af[4], bfr[4];
      #pragma unroll
      for (int mi = 0; mi < 4; ++mi) {
        int R = wm * 64 + mi * 16 + lr;
        int ec = (ks * 32 + lg * 8) ^ ((R & 7) << 3);
        af[mi] = *(const bf16x8*)&ldsA[R * 64 + ec];
      }
      #pragma unroll
      for (int ni = 0; ni < 4; ++ni) {
        int R = wn * 64 + ni * 16 + lr;
        int ec = (ks * 32 + lg * 8) ^ ((R & 7) << 3);
        bfr[ni] = *(const bf16x8*)&ldsB[R * 64 + ec];
      }
      #pragma unroll
      for (int mi = 0; mi < 4; ++mi)
        #pragma unroll
        for (int ni = 0; ni < 4; ++ni)
          acc[mi][ni] = __builtin_amdgcn_mfma_f32_16x16x32_bf16(af[mi], bfr[ni], acc[mi][ni], 0, 0, 0);
    }
    __syncthreads();                     // reads done before next stage
  }

  if (GATES) {
    // LDS-staged epilogue: activated 128x128 C-tile = 32KB overlays smem.
    __hip_bfloat16* Ct = (__hip_bfloat16*)smem;
    const bool isIC = (col0 < 2 * KP);
    #pragma unroll
    for (int ni = 0; ni < 4; ++ni) {
      int cbase = wn * 64 + ni * 16;     // uniform per (wn,ni)
      int cc = cbase + lr;
      // IC tiles: cols 0-63 = i (sig), 64-127 = c (tanh). FO: all sig.
      const bool istanh = isIC && (cbase & 64);
      #pragma unroll
      for (int mi = 0; mi < 4; ++mi) {
        #pragma unroll
        for (int j = 0; j < 4; ++j) {
          int rr = wm * 64 + mi * 16 + lg * 4 + j;
          float v = acc[mi][ni][j];
          Ct[rr * 128 + cc] = __float2bfloat16(istanh ? fast_tanh(v) : softcap_sig(v));
        }
      }
    }
    __syncthreads();
    if (isIC) {
      // emit itc = sig(i)*tanh(c), 64 cols per block
      const int t = col0 >> 7;           // IC tile index 0..21
      #pragma unroll
      for (int it = 0; it < 4; ++it) {
        int idx = it * 256 + tid;        // 0..1023
        int rr = idx >> 3;               // row 0..127
        int ck = idx & 7;                // 8-col chunk 0..7
        u16x4 y[2];
        #pragma unroll
        for (int h = 0; h < 2; ++h) {
          #pragma unroll
          for (int j = 0; j < 4; ++j) {
            int cp = ck * 8 + h * 4 + j;
            float iv = bf2f(*(const unsigned short*)&Ct[rr * 128 + cp]);
            float cv = bf2f(*(const unsigned short*)&Ct[rr * 128 + 64 + cp]);
            y[h][j] = f2bf(iv * cv);
          }
        }
        size_t rl = (size_t)(rl0 + rr);
        int p0 = t * 64 + ck * 8;
        __builtin_nontemporal_store(y[0], reinterpret_cast<u16x4*>(&pitc[rl * KP + p0]));
        __builtin_nontemporal_store(y[1], reinterpret_cast<u16x4*>(&pitc[rl * KP + p0 + 4]));
      }
    } else {
      const int coff = col0 - 2 * KP;    // 0..2KP-128 within [f|o] region
      #pragma unroll
      for (int it = 0; it < 8; ++it) {
        int idx = it * 256 + tid;        // 0..2047
        int rr = idx >> 4;               // row 0..127
        int ck = idx & 15;               // 8-col chunk
        int gn8 = coff + ck * 8;
        int g = gn8 / KP;                // 0=f, 1=o (uniform: 128 | KP)
        int p = gn8 - g * KP;
        __hip_bfloat16* plane = g ? po : pf;
        size_t rl = (size_t)(rl0 + rr);
        __builtin_nontemporal_store(
            *reinterpret_cast<const f32x4*>(&Ct[rr * 128 + ck * 8]),
            reinterpret_cast<f32x4*>(&plane[rl * KP + p]));
      }
    }
  } else {
    #pragma unroll
    for (int ni = 0; ni < 4; ++ni) {
      int gn = col0 + wn * 64 + ni * 16 + lr;
      #pragma unroll
      for (int mi = 0; mi < 4; ++mi) {
        #pragma unroll
        for (int j = 0; j < 4; ++j) {
          int rl = rl0 + wm * 64 + mi * 16 + lg * 4 + j;
          size_t o2 = grow_of(rl) * D_ + gn;
          float xr = __builtin_nontemporal_load(xres + o2);
          __builtin_nontemporal_store(xr + acc[mi][ni][j], out + o2);
        }
      }
    }
  }
}

// ---- scan pass 1: per-chunk affine map (A = prod f, B = f*B + itc) ----
__global__ __launch_bounds__(256) void k_scan_p1(
    const __hip_bfloat16* __restrict__ pitc, const __hip_bfloat16* __restrict__ pf,
    float* __restrict__ Abuf, float* __restrict__ Bbuf, int C) {
  int t = blockIdx.x * blockDim.x + threadIdx.x;   // B_*C*(KP/4) threads
  int p4 = t % (KP / 4);
  int rest = t / (KP / 4);
  int b = rest & 7;
  int c = rest >> 3;
  int p = p4 * 4;
  size_t base = ((size_t)b * C * CHUNK + (size_t)c * CHUNK) * KP + p;
  f32x4 Aa = {1.f, 1.f, 1.f, 1.f};
  f32x4 Bc = {0.f, 0.f, 0.f, 0.f};
  #pragma unroll 8
  for (int sl = 0; sl < CHUNK; ++sl) {
    size_t idx = base + (size_t)sl * KP;
    u16x4 vf = __builtin_nontemporal_load(reinterpret_cast<const u16x4*>(pf + idx));
    u16x4 vt = __builtin_nontemporal_load(reinterpret_cast<const u16x4*>(pitc + idx));
    float f0 = bf2f(vf.x), f1 = bf2f(vf.y), f2 = bf2f(vf.z), f3 = bf2f(vf.w);
    Aa.x *= f0; Aa.y *= f1; Aa.z *= f2; Aa.w *= f3;
    Bc.x = f0 * Bc.x + bf2f(vt.x);
    Bc.y = f1 * Bc.y + bf2f(vt.y);
    Bc.z = f2 * Bc.z + bf2f(vt.z);
    Bc.w = f3 * Bc.w + bf2f(vt.w);
  }
  size_t o = ((size_t)c * B_ + b) * KP + p;
  *reinterpret_cast<f32x4*>(Abuf + o) = Aa;
  *reinterpret_cast<f32x4*>(Bbuf + o) = Bc;
}

// ---- scan pass 2: compose chunk maps; emit per-chunk carry-in + h_final ----
__global__ __launch_bounds__(256) void k_scan_p2(
    const float* __restrict__ Abuf, const float* __restrict__ Bbuf,
    const float* __restrict__ h_in, float* __restrict__ carry,
    float* __restrict__ h_out, int C) {
  int t = blockIdx.x * blockDim.x + threadIdx.x;   // B_*KP threads
  int b = t / KP;
  int p = t - b * KP;
  float h = (p < P_) ? h_in[(size_t)b * P_ + p] : 0.f;
  #pragma unroll 8
  for (int c = 0; c < C; ++c) {
    size_t o = ((size_t)c * B_ + b) * KP + p;
    carry[o] = h;
    h = Abuf[o] * h + Bbuf[o];
  }
  if (p < P_) h_out[(size_t)b * P_ + p] = h;
}

// ---- scan pass 3: replay from carry-in; y = o*tanh(h) in-place into pitc ----
__global__ __launch_bounds__(256) void k_scan_p3(
    __hip_bfloat16* __restrict__ pitc, const __hip_bfloat16* __restrict__ pf,
    const __hip_bfloat16* __restrict__ po,
    const float* __restrict__ carry, int C) {
  int t = blockIdx.x * blockDim.x + threadIdx.x;
  int p4 = t % (KP / 4);
  int rest = t / (KP / 4);
  int b = rest & 7;
  int c = rest >> 3;
  int p = p4 * 4;
  f32x4 h4 = *reinterpret_cast<const f32x4*>(carry + ((size_t)c * B_ + b) * KP + p);
  size_t base = ((size_t)b * C * CHUNK + (size_t)c * CHUNK) * KP + p;
  #pragma unroll 4
  for (int sl = 0; sl < CHUNK; ++sl) {
    size_t idx = base + (size_t)sl * KP;
    u16x4 vf = __builtin_nontemporal_load(reinterpret_cast<const u16x4*>(pf + idx));
    u16x4 vo = __builtin_nontemporal_load(reinterpret_cast<const u16x4*>(po + idx));
    u16x4 vt = __builtin_nontemporal_load(reinterpret_cast<const u16x4*>(pitc + idx));
    h4.x = bf2f(vf.x) * h4.x + bf2f(vt.x);
    h4.y = bf2f(vf.y) * h4.y + bf2f(vt.y);
    h4.z = bf2f(vf.z) * h4.z + bf2f(vt.z);
    h4.w = bf2f(vf.w) * h4.w + bf2f(vt.w);
    u16x4 y;
    y.x = f2bf(bf2f(vo.x) * fast_tanh(h4.x));
    y.y = f2bf(bf2f(vo.y) * fast_tanh(h4.y));
    y.z = f2bf(bf2f(vo.z) * fast_tanh(h4.z));
    y.w = f2bf(bf2f(vo.w) * fast_tanh(h4.w));
    __builtin_nontemporal_store(y, reinterpret_cast<u16x4*>(pitc + idx));
  }
}

extern "C" void kernel_launch(void* const* d_in, const int* in_sizes, int n_in,
                              void* d_out, int out_size, void* d_ws, size_t ws_size,
                              hipStream_t stream) {
  const float* x      = (const float*)d_in[0];
  const float* h0     = (const float*)d_in[1];
  const float* lnw    = (const float*)d_in[2];
  const float* gate_w = (const float*)d_in[3];
  const float* cell_w = (const float*)d_in[4];
  const float* out_w  = (const float*)d_in[5];
  float* out  = (float*)d_out;
  float* hfin = out + (size_t)M_ * D_;

  // fixed workspace
  size_t off = 0;
  char* ws = (char*)d_ws;
  __hip_bfloat16* xn   = (__hip_bfloat16*)(ws + off); off += (size_t)M_ * D_ * 2;
  __hip_bfloat16* wgc  = (__hip_bfloat16*)(ws + off); off += (size_t)NGCP * D_ * 2;
  __hip_bfloat16* wout = (__hip_bfloat16*)(ws + off); off += (size_t)D_ * KP * 2;
  float* hbuf          = (float*)(ws + off);          off += (size_t)B_ * P_ * 4;
  float* Abuf          = (float*)(ws + off);          off += (size_t)CMAX * B_ * KP * 4;
  float* Bbuf          = (float*)(ws + off);          off += (size_t)CMAX * B_ * KP * 4;
  float* carry         = (float*)(ws + off);          off += (size_t)CMAX * B_ * KP * 4;
  off = (off + 255) & ~(size_t)255;

  // pick nchunks so 3 planes fit in remaining ws
  int nchunks = 1;
  while (nchunks < 16) {
    size_t planes = 3ull * B_ * (S_ / nchunks) * KP * 2;
    if (off + planes <= ws_size) break;
    nchunks <<= 1;
  }
  const int Sc = S_ / nchunks;          // power of 2, >= 128
  const int C = Sc / CHUNK;
  int sc_shift = 0;
  while ((1 << sc_shift) < Sc) ++sc_shift;
  __hip_bfloat16* pitc = (__hip_bfloat16*)(ws + off); off += (size_t)B_ * Sc * KP * 2;
  __hip_bfloat16* pf   = (__hip_bfloat16*)(ws + off); off += (size_t)B_ * Sc * KP * 2;
  __hip_bfloat16* po   = (__hip_bfloat16*)(ws + off); off += (size_t)B_ * Sc * KP * 2;

  k_prep_wgc<<<dim3(NGCP * D_ / 1024), dim3(256), 0, stream>>>(gate_w, cell_w, wgc);
  k_prep_wout<<<dim3(D_ * KP / 1024), dim3(256), 0, stream>>>(out_w, wout);
  k_rmsnorm<<<dim3(M_), dim3(256), 0, stream>>>(x, lnw, xn);

  for (int c = 0; c < nchunks; ++c) {
    int s0 = c * Sc;
    const int NBY = B_ * Sc / 128;
    k_gemm128<D_, D_/64, true><<<dim3((NGCP / 128) * NBY), dim3(256), 0, stream>>>(
        xn, wgc, pitc, pf, po, nullptr, nullptr, s0, sc_shift, NBY);
    int np1 = B_ * C * (KP / 4);
    k_scan_p1<<<dim3(np1 / 256), dim3(256), 0, stream>>>(pitc, pf, Abuf, Bbuf, C);
    k_scan_p2<<<dim3(B_ * KP / 256), dim3(256), 0, stream>>>(
        Abuf, Bbuf, (c == 0) ? h0 : hbuf, carry,
        (c == nchunks - 1) ? hfin : hbuf, C);
    k_scan_p3<<<dim3(np1 / 256), dim3(256), 0, stream>>>(pitc, pf, po, carry, C);
    k_gemm128<KP, KP/64, false><<<dim3((D_ / 128) * NBY), dim3(256), 0, stream>>>(
        pitc, wout, nullptr, nullptr, nullptr, x, out, s0, sc_shift, NBY);
  }
}

// Round 19
// 399.582 us; speedup vs baseline: 1.6375x; 1.6375x over previous
//
#include <hip/hip_runtime.h>
#include <hip/hip_bf16.h>
#include <cstdint>

// Problem dims
#define B_   8
#define S_   2048
#define D_   1024
#define P_   1365
#define M_   (B_*S_)      // 16384 rows
#define KP   1408         // per-gate padded width (= 11*128, 22*64)
#define NGCP (4*KP)       // 5632 rows of fused weight; layout:
                          //  [0,2KP):   IC region, 22 tiles of 128 rows =
                          //             [i(64t..64t+64) | c(64t..64t+64)]
                          //  [2KP,3KP): f rows;  [3KP,4KP): o rows
#define CHUNK 32          // scan chunk length
#define CMAX (S_/CHUNK)   // 64

typedef __attribute__((ext_vector_type(8))) short bf16x8;
typedef __attribute__((ext_vector_type(4))) float f32x4;
typedef __attribute__((ext_vector_type(4))) unsigned short u16x4;

__device__ __forceinline__ float fast_rcp(float x) {
  return __builtin_amdgcn_rcpf(x);
}
__device__ __forceinline__ float fast_tanh(float x) {
  float e = __expf(2.0f * x);
  return 1.0f - 2.0f * fast_rcp(e + 1.0f);
}
// sigmoid(15*tanh(x/15)), tanh by 3rd-order poly (|x/15| <= ~0.3 here)
__device__ __forceinline__ float softcap_sig(float x) {
  float u = x * (1.0f / 15.0f);
  float z = -x + x * u * u * (1.0f / 3.0f);   // -15*tanh(x/15) approx
  return fast_rcp(1.0f + __expf(z));
}
__device__ __forceinline__ float bf2f(unsigned short u) {
  union { float f; unsigned int i; } x; x.i = ((unsigned)u) << 16; return x.f;
}
__device__ __forceinline__ unsigned short f2bf(float f) {
  __hip_bfloat16 h = __float2bfloat16(f);
  return *reinterpret_cast<unsigned short*>(&h);
}
__device__ __forceinline__ void gload_lds16(const void* g, void* l) {
  __builtin_amdgcn_global_load_lds(
      (const __attribute__((address_space(1))) uint32_t*)g,
      (__attribute__((address_space(3))) uint32_t*)l,
      16, 0, 0);
}

// ---- prep: weights f32 -> bf16, [i64|c64]x22 + f + o layout ----
__global__ void k_prep_wgc(const float* __restrict__ gate_w,
                           const float* __restrict__ cell_w,
                           __hip_bfloat16* __restrict__ wgc) {
  int gid = blockIdx.x * blockDim.x + threadIdx.x;
  int idx = gid * 4;                       // NGCP*1024 total elems
  int r = idx >> 10, c = idx & 1023;
  f32x4 v = {0.f, 0.f, 0.f, 0.f};
  if (r < 2 * KP) {                        // IC region: tile t, [i64|c64]
    int t = r >> 7, lo = r & 127;
    if (lo < 64) {
      int pr = t * 64 + lo;                // i rows (gate 0)
      if (pr < P_) v = __builtin_nontemporal_load((const f32x4*)(gate_w + (size_t)pr * D_ + c));
    } else {
      int pr = t * 64 + (lo - 64);         // c rows (cell)
      if (pr < P_) v = __builtin_nontemporal_load((const f32x4*)(cell_w + (size_t)pr * D_ + c));
    }
  } else if (r < 3 * KP) {                 // f rows (gate 1)
    int pr = r - 2 * KP;
    if (pr < P_) v = __builtin_nontemporal_load((const f32x4*)(gate_w + (size_t)(P_ + pr) * D_ + c));
  } else {                                 // o rows (gate 2)
    int pr = r - 3 * KP;
    if (pr < P_) v = __builtin_nontemporal_load((const f32x4*)(gate_w + (size_t)(2 * P_ + pr) * D_ + c));
  }
  __hip_bfloat16* dst = wgc + idx;
  dst[0] = __float2bfloat16(v.x); dst[1] = __float2bfloat16(v.y);
  dst[2] = __float2bfloat16(v.z); dst[3] = __float2bfloat16(v.w);
}

__global__ void k_prep_wout(const float* __restrict__ out_w,
                            __hip_bfloat16* __restrict__ wout) {
  int gid = blockIdx.x * blockDim.x + threadIdx.x;
  int idx = gid * 4;                       // 1024*1408 total elems
  int d = idx / KP, p = idx - d * KP;
  __hip_bfloat16* dst = wout + idx;
  #pragma unroll
  for (int j = 0; j < 4; ++j) {
    int pp = p + j;
    float v = (pp < P_) ? __builtin_nontemporal_load(out_w + (size_t)d * P_ + pp) : 0.f;
    dst[j] = __float2bfloat16(v);
  }
}

// ---- RMSNorm: per row of D=1024, write bf16 ----
__global__ __launch_bounds__(256) void k_rmsnorm(const float* __restrict__ x,
                                                 const float* __restrict__ w,
                                                 __hip_bfloat16* __restrict__ xn) {
  __shared__ float red[4];
  int m = blockIdx.x;
  int tid = threadIdx.x;
  f32x4 v = __builtin_nontemporal_load(((const f32x4*)(x + (size_t)m * D_)) + tid);
  float ss = v.x * v.x + v.y * v.y + v.z * v.z + v.w * v.w;
  #pragma unroll
  for (int off = 32; off > 0; off >>= 1) ss += __shfl_down(ss, off);
  if ((tid & 63) == 0) red[tid >> 6] = ss;
  __syncthreads();
  float tot = red[0] + red[1] + red[2] + red[3];
  float scale = rsqrtf(tot * (1.0f / (float)D_) + 1e-6f);
  f32x4 wv = ((const f32x4*)w)[tid];
  __hip_bfloat16* o = xn + (size_t)m * D_ + tid * 4;
  o[0] = __float2bfloat16(v.x * scale * wv.x);
  o[1] = __float2bfloat16(v.y * scale * wv.y);
  o[2] = __float2bfloat16(v.z * scale * wv.z);
  o[3] = __float2bfloat16(v.w * scale * wv.w);
}

// ============================================================================
// 128x128-tile GEMM, BK=64, 4 waves (2M x 2N), single-buffered 32KB LDS,
// __launch_bounds__(256,4): r17-measured VGPR=64 / zero spill / 4 blocks/CU.
// (r18's (256,5) forced VGPR 48 -> accumulator spill: WRITE 135->522MB,
// MfmaUtil 37->18%. Reverted.)
// m97/m103 structure: cross-block TLP hides the barrier drain.
// T2 source-swizzle, LDS-staged GATES epilogue, itc fusion, NT plane stores.
// bx-CHUNKED XCD mapping (r18-verified: FETCH 590->236MB): within each
// XCD's by-band, process bx in chunks of 11 so the concurrent B working
// set is ~2.75MB instead of 11.5MB.
// ============================================================================
template<int LDK, int KT, bool GATES>
__global__ __launch_bounds__(256, 4) void k_gemm128(
    const __hip_bfloat16* __restrict__ A,
    const __hip_bfloat16* __restrict__ Bw,
    __hip_bfloat16* __restrict__ pitc, __hip_bfloat16* __restrict__ pf,
    __hip_bfloat16* __restrict__ po,
    const float* __restrict__ xres, float* __restrict__ out,
    int s0, int sc_shift, int NBY) {
  __shared__ __align__(16) char smem[32768];   // A 16KB + B 16KB (single buf)
  __hip_bfloat16* ldsA = (__hip_bfloat16*)smem;             // [128*64]
  __hip_bfloat16* ldsB = (__hip_bfloat16*)(smem + 16384);   // [128*64]
  const int tid = threadIdx.x;
  const int lane = tid & 63;
  const int wid = tid >> 6;            // 0..3
  const int wm = wid >> 1, wn = wid & 1;
  const int lr = lane & 15, lg = lane >> 4;

  // XCD-chunked bijection with bx-chunking (gridDim.x divisible by 8).
  const int NX = gridDim.x / NBY;
  const int NBYX = NBY >> 3;           // by-rows per XCD
  const int xcd = blockIdx.x & 7;
  const int L = blockIdx.x >> 3;       // 0..cpx-1, cpx = NX*NBYX
  const int W = (NX % 11 == 0) ? 11 : NX;   // bx chunk width
  const int bpc = W * NBYX;
  const int ch = L / bpc;
  const int l2 = L - ch * bpc;
  const int byl = l2 / W;
  const int bxl = l2 - byl * W;
  const int bx = ch * W + bxl;
  const int by = xcd * NBYX + byl;
  const int rl0 = by * 128;            // chunk-local row
  const int col0 = bx * 128;
  const int scm = (1 << sc_shift) - 1;

  auto grow_of = [&](int rl) -> size_t {   // chunk-local row -> global row
    int bb = rl >> sc_shift;
    return (size_t)bb * S_ + s0 + (rl & scm);
  };

  auto stage = [&](int kt) {
    const int k0 = kt * 64;
    #pragma unroll
    for (int it = 0; it < 4; ++it) {
      int off = (it * 256 + tid) * 8;     // 0..8191
      int r = off >> 6, c = off & 63;
      int csrc = c ^ ((r & 7) << 3);      // pre-swizzled source column
      size_t ar = GATES ? grow_of(rl0 + r) : (size_t)(rl0 + r);
      gload_lds16(A + ar * LDK + k0 + csrc, ldsA + off);
      gload_lds16(Bw + (size_t)(col0 + r) * LDK + k0 + csrc, ldsB + off);
    }
  };

  const f32x4 zero = {0.f, 0.f, 0.f, 0.f};
  f32x4 acc[4][4];
  #pragma unroll
  for (int i = 0; i < 4; ++i)
    #pragma unroll
    for (int j = 0; j < 4; ++j) acc[i][j] = zero;

  for (int kt = 0; kt < KT; ++kt) {
    stage(kt);
    __syncthreads();                     // loads resident
    #pragma unroll
    for (int ks = 0; ks < 2; ++ks) {
      bf16x8 af[4], bfr[4];
      #pragma unroll
      for (int mi = 0; mi < 4; ++mi) {
        int R = wm * 64 + mi * 16 + lr;
        int ec = (ks * 32 + lg * 8) ^ ((R & 7) << 3);
        af[mi] = *(const bf16x8*)&ldsA[R * 64 + ec];
      }
      #pragma unroll
      for (int ni = 0; ni < 4; ++ni) {
        int R = wn * 64 + ni * 16 + lr;
        int ec = (ks * 32 + lg * 8) ^ ((R & 7) << 3);
        bfr[ni] = *(const bf16x8*)&ldsB[R * 64 + ec];
      }
      #pragma unroll
      for (int mi = 0; mi < 4; ++mi)
        #pragma unroll
        for (int ni = 0; ni < 4; ++ni)
          acc[mi][ni] = __builtin_amdgcn_mfma_f32_16x16x32_bf16(af[mi], bfr[ni], acc[mi][ni], 0, 0, 0);
    }
    __syncthreads();                     // reads done before next stage
  }

  if (GATES) {
    // LDS-staged epilogue: activated 128x128 C-tile = 32KB overlays smem.
    __hip_bfloat16* Ct = (__hip_bfloat16*)smem;
    const bool isIC = (col0 < 2 * KP);
    #pragma unroll
    for (int ni = 0; ni < 4; ++ni) {
      int cbase = wn * 64 + ni * 16;     // uniform per (wn,ni)
      int cc = cbase + lr;
      // IC tiles: cols 0-63 = i (sig), 64-127 = c (tanh). FO: all sig.
      const bool istanh = isIC && (cbase & 64);
      #pragma unroll
      for (int mi = 0; mi < 4; ++mi) {
        #pragma unroll
        for (int j = 0; j < 4; ++j) {
          int rr = wm * 64 + mi * 16 + lg * 4 + j;
          float v = acc[mi][ni][j];
          Ct[rr * 128 + cc] = __float2bfloat16(istanh ? fast_tanh(v) : softcap_sig(v));
        }
      }
    }
    __syncthreads();
    if (isIC) {
      // emit itc = sig(i)*tanh(c), 64 cols per block
      const int t = col0 >> 7;           // IC tile index 0..21
      #pragma unroll
      for (int it = 0; it < 4; ++it) {
        int idx = it * 256 + tid;        // 0..1023
        int rr = idx >> 3;               // row 0..127
        int ck = idx & 7;                // 8-col chunk 0..7
        u16x4 y[2];
        #pragma unroll
        for (int h = 0; h < 2; ++h) {
          #pragma unroll
          for (int j = 0; j < 4; ++j) {
            int cp = ck * 8 + h * 4 + j;
            float iv = bf2f(*(const unsigned short*)&Ct[rr * 128 + cp]);
            float cv = bf2f(*(const unsigned short*)&Ct[rr * 128 + 64 + cp]);
            y[h][j] = f2bf(iv * cv);
          }
        }
        size_t rl = (size_t)(rl0 + rr);
        int p0 = t * 64 + ck * 8;
        __builtin_nontemporal_store(y[0], reinterpret_cast<u16x4*>(&pitc[rl * KP + p0]));
        __builtin_nontemporal_store(y[1], reinterpret_cast<u16x4*>(&pitc[rl * KP + p0 + 4]));
      }
    } else {
      const int coff = col0 - 2 * KP;    // 0..2KP-128 within [f|o] region
      #pragma unroll
      for (int it = 0; it < 8; ++it) {
        int idx = it * 256 + tid;        // 0..2047
        int rr = idx >> 4;               // row 0..127
        int ck = idx & 15;               // 8-col chunk
        int gn8 = coff + ck * 8;
        int g = gn8 / KP;                // 0=f, 1=o (uniform: 128 | KP)
        int p = gn8 - g * KP;
        __hip_bfloat16* plane = g ? po : pf;
        size_t rl = (size_t)(rl0 + rr);
        __builtin_nontemporal_store(
            *reinterpret_cast<const f32x4*>(&Ct[rr * 128 + ck * 8]),
            reinterpret_cast<f32x4*>(&plane[rl * KP + p]));
      }
    }
  } else {
    #pragma unroll
    for (int ni = 0; ni < 4; ++ni) {
      int gn = col0 + wn * 64 + ni * 16 + lr;
      #pragma unroll
      for (int mi = 0; mi < 4; ++mi) {
        #pragma unroll
        for (int j = 0; j < 4; ++j) {
          int rl = rl0 + wm * 64 + mi * 16 + lg * 4 + j;
          size_t o2 = grow_of(rl) * D_ + gn;
          float xr = __builtin_nontemporal_load(xres + o2);
          __builtin_nontemporal_store(xr + acc[mi][ni][j], out + o2);
        }
      }
    }
  }
}

// ---- scan pass 1: per-chunk affine map (A = prod f, B = f*B + itc) ----
__global__ __launch_bounds__(256) void k_scan_p1(
    const __hip_bfloat16* __restrict__ pitc, const __hip_bfloat16* __restrict__ pf,
    float* __restrict__ Abuf, float* __restrict__ Bbuf, int C) {
  int t = blockIdx.x * blockDim.x + threadIdx.x;   // B_*C*(KP/4) threads
  int p4 = t % (KP / 4);
  int rest = t / (KP / 4);
  int b = rest & 7;
  int c = rest >> 3;
  int p = p4 * 4;
  size_t base = ((size_t)b * C * CHUNK + (size_t)c * CHUNK) * KP + p;
  f32x4 Aa = {1.f, 1.f, 1.f, 1.f};
  f32x4 Bc = {0.f, 0.f, 0.f, 0.f};
  #pragma unroll 8
  for (int sl = 0; sl < CHUNK; ++sl) {
    size_t idx = base + (size_t)sl * KP;
    u16x4 vf = __builtin_nontemporal_load(reinterpret_cast<const u16x4*>(pf + idx));
    u16x4 vt = __builtin_nontemporal_load(reinterpret_cast<const u16x4*>(pitc + idx));
    float f0 = bf2f(vf.x), f1 = bf2f(vf.y), f2 = bf2f(vf.z), f3 = bf2f(vf.w);
    Aa.x *= f0; Aa.y *= f1; Aa.z *= f2; Aa.w *= f3;
    Bc.x = f0 * Bc.x + bf2f(vt.x);
    Bc.y = f1 * Bc.y + bf2f(vt.y);
    Bc.z = f2 * Bc.z + bf2f(vt.z);
    Bc.w = f3 * Bc.w + bf2f(vt.w);
  }
  size_t o = ((size_t)c * B_ + b) * KP + p;
  *reinterpret_cast<f32x4*>(Abuf + o) = Aa;
  *reinterpret_cast<f32x4*>(Bbuf + o) = Bc;
}

// ---- scan pass 2: compose chunk maps; emit per-chunk carry-in + h_final ----
__global__ __launch_bounds__(256) void k_scan_p2(
    const float* __restrict__ Abuf, const float* __restrict__ Bbuf,
    const float* __restrict__ h_in, float* __restrict__ carry,
    float* __restrict__ h_out, int C) {
  int t = blockIdx.x * blockDim.x + threadIdx.x;   // B_*KP threads
  int b = t / KP;
  int p = t - b * KP;
  float h = (p < P_) ? h_in[(size_t)b * P_ + p] : 0.f;
  #pragma unroll 8
  for (int c = 0; c < C; ++c) {
    size_t o = ((size_t)c * B_ + b) * KP + p;
    carry[o] = h;
    h = Abuf[o] * h + Bbuf[o];
  }
  if (p < P_) h_out[(size_t)b * P_ + p] = h;
}

// ---- scan pass 3: replay from carry-in; y = o*tanh(h) in-place into pitc ----
__global__ __launch_bounds__(256) void k_scan_p3(
    __hip_bfloat16* __restrict__ pitc, const __hip_bfloat16* __restrict__ pf,
    const __hip_bfloat16* __restrict__ po,
    const float* __restrict__ carry, int C) {
  int t = blockIdx.x * blockDim.x + threadIdx.x;
  int p4 = t % (KP / 4);
  int rest = t / (KP / 4);
  int b = rest & 7;
  int c = rest >> 3;
  int p = p4 * 4;
  f32x4 h4 = *reinterpret_cast<const f32x4*>(carry + ((size_t)c * B_ + b) * KP + p);
  size_t base = ((size_t)b * C * CHUNK + (size_t)c * CHUNK) * KP + p;
  #pragma unroll 4
  for (int sl = 0; sl < CHUNK; ++sl) {
    size_t idx = base + (size_t)sl * KP;
    u16x4 vf = __builtin_nontemporal_load(reinterpret_cast<const u16x4*>(pf + idx));
    u16x4 vo = __builtin_nontemporal_load(reinterpret_cast<const u16x4*>(po + idx));
    u16x4 vt = __builtin_nontemporal_load(reinterpret_cast<const u16x4*>(pitc + idx));
    h4.x = bf2f(vf.x) * h4.x + bf2f(vt.x);
    h4.y = bf2f(vf.y) * h4.y + bf2f(vt.y);
    h4.z = bf2f(vf.z) * h4.z + bf2f(vt.z);
    h4.w = bf2f(vf.w) * h4.w + bf2f(vt.w);
    u16x4 y;
    y.x = f2bf(bf2f(vo.x) * fast_tanh(h4.x));
    y.y = f2bf(bf2f(vo.y) * fast_tanh(h4.y));
    y.z = f2bf(bf2f(vo.z) * fast_tanh(h4.z));
    y.w = f2bf(bf2f(vo.w) * fast_tanh(h4.w));
    __builtin_nontemporal_store(y, reinterpret_cast<u16x4*>(pitc + idx));
  }
}

extern "C" void kernel_launch(void* const* d_in, const int* in_sizes, int n_in,
                              void* d_out, int out_size, void* d_ws, size_t ws_size,
                              hipStream_t stream) {
  const float* x      = (const float*)d_in[0];
  const float* h0     = (const float*)d_in[1];
  const float* lnw    = (const float*)d_in[2];
  const float* gate_w = (const float*)d_in[3];
  const float* cell_w = (const float*)d_in[4];
  const float* out_w  = (const float*)d_in[5];
  float* out  = (float*)d_out;
  float* hfin = out + (size_t)M_ * D_;

  // fixed workspace
  size_t off = 0;
  char* ws = (char*)d_ws;
  __hip_bfloat16* xn   = (__hip_bfloat16*)(ws + off); off += (size_t)M_ * D_ * 2;
  __hip_bfloat16* wgc  = (__hip_bfloat16*)(ws + off); off += (size_t)NGCP * D_ * 2;
  __hip_bfloat16* wout = (__hip_bfloat16*)(ws + off); off += (size_t)D_ * KP * 2;
  float* hbuf          = (float*)(ws + off);          off += (size_t)B_ * P_ * 4;
  float* Abuf          = (float*)(ws + off);          off += (size_t)CMAX * B_ * KP * 4;
  float* Bbuf          = (float*)(ws + off);          off += (size_t)CMAX * B_ * KP * 4;
  float* carry         = (float*)(ws + off);          off += (size_t)CMAX * B_ * KP * 4;
  off = (off + 255) & ~(size_t)255;

  // pick nchunks so 3 planes fit in remaining ws
  int nchunks = 1;
  while (nchunks < 16) {
    size_t planes = 3ull * B_ * (S_ / nchunks) * KP * 2;
    if (off + planes <= ws_size) break;
    nchunks <<= 1;
  }
  const int Sc = S_ / nchunks;          // power of 2, >= 128
  const int C = Sc / CHUNK;
  int sc_shift = 0;
  while ((1 << sc_shift) < Sc) ++sc_shift;
  __hip_bfloat16* pitc = (__hip_bfloat16*)(ws + off); off += (size_t)B_ * Sc * KP * 2;
  __hip_bfloat16* pf   = (__hip_bfloat16*)(ws + off); off += (size_t)B_ * Sc * KP * 2;
  __hip_bfloat16* po   = (__hip_bfloat16*)(ws + off); off += (size_t)B_ * Sc * KP * 2;

  k_prep_wgc<<<dim3(NGCP * D_ / 1024), dim3(256), 0, stream>>>(gate_w, cell_w, wgc);
  k_prep_wout<<<dim3(D_ * KP / 1024), dim3(256), 0, stream>>>(out_w, wout);
  k_rmsnorm<<<dim3(M_), dim3(256), 0, stream>>>(x, lnw, xn);

  for (int c = 0; c < nchunks; ++c) {
    int s0 = c * Sc;
    const int NBY = B_ * Sc / 128;
    k_gemm128<D_, D_/64, true><<<dim3((NGCP / 128) * NBY), dim3(256), 0, stream>>>(
        xn, wgc, pitc, pf, po, nullptr, nullptr, s0, sc_shift, NBY);
    int np1 = B_ * C * (KP / 4);
    k_scan_p1<<<dim3(np1 / 256), dim3(256), 0, stream>>>(pitc, pf, Abuf, Bbuf, C);
    k_scan_p2<<<dim3(B_ * KP / 256), dim3(256), 0, stream>>>(
        Abuf, Bbuf, (c == 0) ? h0 : hbuf, carry,
        (c == nchunks - 1) ? hfin : hbuf, C);
    k_scan_p3<<<dim3(np1 / 256), dim3(256), 0, stream>>>(pitc, pf, po, carry, C);
    k_gemm128<KP, KP/64, false><<<dim3((D_ / 128) * NBY), dim3(256), 0, stream>>>(
        pitc, wout, nullptr, nullptr, nullptr, x, out, s0, sc_shift, NBY);
  }
}